// Round 9
// baseline (494.573 us; speedup 1.0000x reference)
//
#include <hip/hip_runtime.h>
#include <hip/hip_bf16.h>
#include <math.h>

// Problem dims
#define B_  64
#define T_  256
#define F_  128
#define H_  8
#define E_  1024   // F*H
#define NH_ 4
#define HD_ 256    // E/NH
#define D_  256

// output element offsets within d_out (element units of the storage dtype)
#define OFF_Y_  0L
#define OFF_FI_ 4194304L
#define OFF_IA_ 4210688L

typedef unsigned short u16;
typedef unsigned int   u32;
typedef short bf16x8 __attribute__((ext_vector_type(8)));
typedef float f32x4  __attribute__((ext_vector_type(4)));

__device__ __forceinline__ float bf2f(u16 u) {
  union { u32 u; float f; } x; x.u = ((u32)u) << 16; return x.f;
}
__device__ __forceinline__ u16 f2bf(float f) {
  union { float f; u32 u; } x; x.f = f;
  u32 r = (x.u + 0x7fffu + ((x.u >> 16) & 1u)) >> 16;
  return (u16)r;
}
__device__ __forceinline__ float gelu_exact(float v) {
  return 0.5f * v * (1.f + erff(v * 0.70710678118654752f));
}
__device__ __forceinline__ float sigmoidf_(float v) {
  return 1.f / (1.f + __expf(-v));
}
__device__ __forceinline__ float ldv(const void* p, long i, bool isf) {
  return isf ? ((const float*)p)[i] : bf2f(((const u16*)p)[i]);
}
__device__ __forceinline__ void stv(void* p, long i, float v, bool isf) {
  if (isf) ((float*)p)[i] = v;
  else ((u16*)p)[i] = f2bf(v);
}
// async global->LDS, 16B/lane: LDS dest = wave-uniform base + lane*16 (HW)
__device__ __forceinline__ void gld16(void* lds, const void* g) {
  __builtin_amdgcn_global_load_lds(
      (const __attribute__((address_space(1))) u32*)g,
      (__attribute__((address_space(3))) u32*)lds, 16, 0, 0);
}
__device__ __forceinline__ void bar_() {
  __builtin_amdgcn_sched_barrier(0);
  __builtin_amdgcn_s_barrier();
  __builtin_amdgcn_sched_barrier(0);
}
#define VMCNTN(n) asm volatile("s_waitcnt vmcnt(" #n ")" ::: "memory")

// ---------------------------------------------------------------------------
// dtype detector (flag: 0 = bf16 storage, 1 = f32 storage)
// ---------------------------------------------------------------------------
__global__ void detect_dtype(const u16* __restrict__ x, u32* __restrict__ flag) {
  if (threadIdx.x == 0 && blockIdx.x == 0) {
    int good = 0;
    for (int i = 0; i < 512; ++i) {
      u16 v = x[i];
      int e = (v >> 7) & 0xFF;
      if (v == 0 || (e >= 100 && e <= 140)) ++good;
    }
    *flag = (good >= 450) ? 0u : 1u;
  }
}

__global__ __launch_bounds__(256)
void convert_in(const void* __restrict__ src, u16* __restrict__ dst, int n,
                const u32* __restrict__ flag) {
  const bool isf = (*flag != 0);
  int i = blockIdx.x * 256 + threadIdx.x;
  if (i < n) dst[i] = isf ? f2bf(((const float*)src)[i]) : ((const u16*)src)[i];
}

// fused transpose + convert: out[c][r] (bf16) = in[r][c] (raw). dims %32 == 0
__global__ void transpose_cvt(const void* __restrict__ in, u16* __restrict__ out,
                              int R, int C, const u32* __restrict__ flag) {
  const bool isf = (*flag != 0);
  __shared__ float t[32][33];
  const int c0 = blockIdx.x * 32, r0 = blockIdx.y * 32;
  const int tx = threadIdx.x, ty = threadIdx.y;
  for (int i = ty; i < 32; i += 8)
    t[i][tx] = ldv(in, (long)(r0 + i) * C + c0 + tx, isf);
  __syncthreads();
  for (int i = ty; i < 32; i += 8)
    out[(long)(c0 + i) * R + r0 + tx] = f2bf(t[tx][i]);
}

// ---------------------------------------------------------------------------
// K1: input-attention MLP (unchanged, passing)
// ---------------------------------------------------------------------------
__global__ __launch_bounds__(128)
void input_mlp2(const void* __restrict__ x,
                const void* __restrict__ w1, const void* __restrict__ b1,
                const void* __restrict__ w2, const void* __restrict__ b2,
                const u32* __restrict__ flag,
                u16* __restrict__ xg, void* __restrict__ dout) {
  const bool isf = (*flag != 0);
  const long row = blockIdx.x;
  const int tid = threadIdx.x;
  __shared__ float xr[F_];
  __shared__ float hid[32];
  __shared__ float red[2];
  float xv = ldv(x, row * F_ + tid, isf);
  xr[tid] = xv;
  __syncthreads();
  if (tid < 32) {
    float s = ldv(b1, tid, isf);
    for (int f = 0; f < F_; ++f) s += xr[f] * ldv(w1, f * 32 + tid, isf);
    hid[tid] = gelu_exact(s);
  }
  __syncthreads();
  float s = ldv(b2, tid, isf);
  #pragma unroll 8
  for (int j = 0; j < 32; ++j) s += hid[j] * ldv(w2, j * F_ + tid, isf);
  float ia = sigmoidf_(s);
  stv(dout, OFF_IA_ + row * F_ + tid, ia, isf);
  xg[row * F_ + tid] = f2bf(ia * xv);
  float v = ia;
  for (int o = 32; o > 0; o >>= 1) v += __shfl_down(v, o);
  if ((tid & 63) == 0) red[tid >> 6] = v;
  __syncthreads();
  if (tid == 0) stv(dout, OFF_FI_ + row, red[0] + red[1], isf);
}

// ---------------------------------------------------------------------------
// K2 v4: GRU bank (unchanged, passing)
// ---------------------------------------------------------------------------
__global__ __launch_bounds__(256)
void gru_scan4(const u16* __restrict__ xg, const void* __restrict__ W_ih,
               const void* __restrict__ W_hh, const void* __restrict__ b_ih,
               const void* __restrict__ b_hh, const u32* __restrict__ flag,
               u16* __restrict__ gruo) {
  const bool isf = (*flag != 0);
  const int tid = threadIdx.x;
  const int ric = tid >> 3;
  const int j   = tid & 7;
  const int rec = blockIdx.x * 32 + ric;
  const int b = rec >> 7, f = rec & 127;
  __shared__ __align__(16) float hbuf[32][8];
  float whr[8], whz[8], whn[8];
  #pragma unroll
  for (int k = 0; k < 8; ++k) {
    whr[k] = ldv(W_hh, (long)f * 192 + j * 8 + k, isf);
    whz[k] = ldv(W_hh, (long)f * 192 + (8 + j) * 8 + k, isf);
    whn[k] = ldv(W_hh, (long)f * 192 + (16 + j) * 8 + k, isf);
  }
  const float wir = ldv(W_ih, f * 24 + j, isf);
  const float wiz = ldv(W_ih, f * 24 + 8 + j, isf);
  const float win = ldv(W_ih, f * 24 + 16 + j, isf);
  const float cbr = ldv(b_ih, f * 24 + j, isf) + ldv(b_hh, f * 24 + j, isf);
  const float cbz = ldv(b_ih, f * 24 + 8 + j, isf) + ldv(b_hh, f * 24 + 8 + j, isf);
  const float bin_ = ldv(b_ih, f * 24 + 16 + j, isf);
  const float bhn_ = ldv(b_hh, f * 24 + 16 + j, isf);
  float h[8];
  #pragma unroll
  for (int k = 0; k < 8; ++k) h[k] = 0.f;
  const u16* xp = xg + (long)b * T_ * F_ + f;
  u16* op = gruo + (long)b * T_ * E_ + f * 8 + j;
  float xv = bf2f(xp[0]);
  for (int t = 0; t < T_; ++t) {
    float xn = (t + 1 < T_) ? bf2f(xp[(t + 1) * F_]) : 0.f;
    float ar = fmaf(xv, wir, cbr);
    float az = fmaf(xv, wiz, cbz);
    float an = bhn_;
    #pragma unroll
    for (int k = 0; k < 8; ++k) {
      ar = fmaf(h[k], whr[k], ar);
      az = fmaf(h[k], whz[k], az);
      an = fmaf(h[k], whn[k], an);
    }
    const float r = sigmoidf_(ar);
    const float z = sigmoidf_(az);
    const float a = fmaf(r, an, fmaf(xv, win, bin_));
    const float e = __expf(2.f * a);
    const float n = 1.f - 2.f / (e + 1.f);
    const float hn = fmaf(z, h[j] - n, n);
    op[(long)t * E_] = f2bf(hn);
    hbuf[ric][j] = hn;
    f32x4 h0 = *(const f32x4*)&hbuf[ric][0];
    f32x4 h1 = *(const f32x4*)&hbuf[ric][4];
    h[0] = h0[0]; h[1] = h0[1]; h[2] = h0[2]; h[3] = h0[3];
    h[4] = h1[0]; h[5] = h1[1]; h[6] = h1[2]; h[7] = h1[3];
    xv = xn;
  }
}

// ---------------------------------------------------------------------------
// 8-phase 256x256 GEMM (T3+T4): BK=32, 8 waves (2Mx4N), dbuf'd 64KB LDS,
// raw s_barrier + counted vmcnt (never drain-0 mid-loop). bt-form, +bias.
// Stage invariant: every gld16 targets a region whose reads completed >=1
// barrier earlier. ph2 entry: vmcnt(2) (vmcnt(0) on last iter - exactly-N
// outstanding would make the counted wait a no-op); loop bottom: vmcnt(2).
// ---------------------------------------------------------------------------
__global__ __launch_bounds__(512, 1)
void gemm8p(const u16* __restrict__ A, int lda,
            const u16* __restrict__ Bp, int ldb,
            u16* __restrict__ Cg, int ldc,
            const u16* __restrict__ bias,
            int K, int nbm, int nwg) {
  // XCD-bijective swizzle (m204)
  const int bid = blockIdx.x;
  const int q8 = nwg >> 3, r8 = nwg & 7;
  const int xcd = bid & 7, off = bid >> 3;
  const int wg = (xcd < r8) ? xcd * (q8 + 1) + off
                            : r8 * (q8 + 1) + (xcd - r8) * q8 + off;
  const int bm = wg % nbm, bn = wg / nbm;
  const long m0 = (long)bm * 256, n0 = (long)bn * 256;
  const int tid = threadIdx.x;
  const int wid = tid >> 6, lane = tid & 63;
  const int wm = wid >> 2, wn = wid & 3;
  const int lr = lane & 15, lq = lane >> 4;
  const int co = ((lq ^ ((lr >> 1) & 3)) << 3);      // read-side un-swizzle (elems)
  __shared__ __align__(16) u16 As[2][2][4096];       // [dbuf][half][128*32]
  __shared__ __align__(16) u16 Bs[2][2][4096];
  const int srow = lane >> 2;                        // staging row within 16-row slab
  const int scsw = (((lane & 3) ^ ((lane >> 3) & 3)) << 3);  // swizzled src col
  const u16* Aw = A + (m0 + wid * 16 + srow) * (long)lda + scsw;
  const u16* Bw = Bp + (n0 + wid * 16 + srow) * (long)ldb + scsw;
  const long ha = 128L * lda, hb = 128L * ldb;

  f32x4 acc[8][4] = {};
  const int nk = K >> 5;
  const int L = (nk >> 1) - 1;

#define STA(d, h, kt) gld16(&As[d][h][wid * 512], Aw + (h) * ha + (kt) * 32)
#define STB(d, h, kt) gld16(&Bs[d][h][wid * 512], Bw + (h) * hb + (kt) * 32)
#define RDA(d, ib, v) { _Pragma("unroll") for (int i2 = 0; i2 < 4; ++i2) \
    v[i2] = *(const bf16x8*)&As[d][wm][((ib) * 16 + i2 * 16 + lr) * 32 + co]; }
#define RDB(d, v) { _Pragma("unroll") for (int jj = 0; jj < 4; ++jj) \
    v[jj] = *(const bf16x8*)&Bs[d][wn >> 1][((wn & 1) * 64 + jj * 16 + lr) * 32 + co]; }
#define MM16(IB, AV, BV) { _Pragma("unroll") for (int i2 = 0; i2 < 4; ++i2) { \
    _Pragma("unroll") for (int jj = 0; jj < 4; ++jj) \
      acc[(IB) + i2][jj] = __builtin_amdgcn_mfma_f32_16x16x32_bf16(AV[i2], BV[jj], acc[(IB) + i2][jj], 0, 0, 0); } }

  // prologue: ktile0 full -> dbuf0; ktile1 B -> dbuf1
  STA(0, 0, 0); STA(0, 1, 0); STB(0, 0, 0); STB(0, 1, 0);
  STB(1, 0, 1); STB(1, 1, 1);
  VMCNTN(2); bar_();

  for (int it = 0; ; ++it) {
    const int t2 = 2 * it + 2, t3 = 2 * it + 3;
    const bool more = (it < L);
    bf16x8 a[4], b[4];
    // ph0: ktile 2it (d0): B all + A quad0; stage d1.A (ktile 2it+1)
    RDB(0, b); RDA(0, 0, a);
    STA(1, 0, t2 - 1); STA(1, 1, t2 - 1);
    bar_(); MM16(0, a, b); bar_();
    // ph1: A quad1 (d0); stage d0'.B
    RDA(0, 4, a);
    if (more) { STB(0, 0, t2); STB(0, 1, t2); }
    bar_(); MM16(4, a, b); bar_();
    // ph2: ktile 2it+1 (d1): B all + A quad0; stage d0'.A
    if (more) { VMCNTN(2); } else { VMCNTN(0); }
    RDB(1, b); RDA(1, 0, a);
    if (more) { STA(0, 0, t2); STA(0, 1, t2); }
    bar_(); MM16(0, a, b); bar_();
    // ph3: A quad1 (d1); stage d1'.B
    RDA(1, 4, a);
    if (more) { STB(1, 0, t3); STB(1, 1, t3); }
    bar_(); MM16(4, a, b); bar_();
    if (!more) break;
    VMCNTN(2);
  }
  // epilogue: C/D layout col=lane&15, row=(lane>>4)*4+q
  #pragma unroll
  for (int i = 0; i < 8; ++i) {
    #pragma unroll
    for (int j = 0; j < 4; ++j) {
      const long col = n0 + wn * 64 + j * 16 + lr;
      const float bv = bf2f(bias[col]);
      #pragma unroll
      for (int qq = 0; qq < 4; ++qq) {
        const long row = m0 + wm * 128 + i * 16 + lq * 4 + qq;
        Cg[row * (long)ldc + col] = f2bf(acc[i][j][qq] + bv);
      }
    }
  }
#undef STA
#undef STB
#undef RDA
#undef RDB
#undef MM16
}

// ---------------------------------------------------------------------------
// bt-form MFMA GEMM v2 (unchanged, passing): 128x128, BK=64, swizzled gld16.
// EPI: 0=none, 1=+bias, 2=+bias+gelu, 3=+bias+resid. COUT: dtype-flagged y.
// ---------------------------------------------------------------------------
template <int EPI, int COUT>
__global__ __launch_bounds__(256)
void gemm_bt(const u16* __restrict__ A, int lda,
             const u16* __restrict__ Bp, int ldb,
             void* __restrict__ Cg, int ldc,
             const u16* __restrict__ bias, const u16* __restrict__ resid,
             int K, int nbm, const u32* __restrict__ flag) {
  const bool isf = (*flag != 0);
  const int bm = blockIdx.x % nbm, bn = blockIdx.x / nbm;
  const int w = threadIdx.x >> 6, lane = threadIdx.x & 63;
  __shared__ __align__(16) u16 As[128 * 64];
  __shared__ __align__(16) u16 Bs[128 * 64];
  const long m0 = (long)bm * 128, n0 = (long)bn * 128;
  const int wm = w >> 1, wn = w & 1;
  const int lr8 = lane >> 3;
  const int csw = ((lane & 7) ^ (lr8 & 7)) * 8;
  f32x4 acc[4][4] = {};
  const int nk = K >> 6;
  const int lr = lane & 15, lq = lane >> 4;
  for (int kt = 0; kt < nk; ++kt) {
    const int k0 = kt << 6;
    __syncthreads();
    #pragma unroll
    for (int c = 0; c < 4; ++c) {
      const int rb = w * 32 + c * 8;
      gld16((char*)As + rb * 128, A + (m0 + rb + lr8) * (long)lda + k0 + csw);
      gld16((char*)Bs + rb * 128, Bp + (n0 + rb + lr8) * (long)ldb + k0 + csw);
    }
    __syncthreads();
    #pragma unroll
    for (int sub = 0; sub < 2; ++sub) {
      const int ch = sub * 4 + lq;
      const int cof = ((ch ^ (lr & 7)) << 3);
      bf16x8 af[4], bfv[4];
      #pragma unroll
      for (int i = 0; i < 4; ++i)
        af[i] = *(const bf16x8*)&As[(wm * 64 + i * 16 + lr) * 64 + cof];
      #pragma unroll
      for (int i = 0; i < 4; ++i)
        bfv[i] = *(const bf16x8*)&Bs[(wn * 64 + i * 16 + lr) * 64 + cof];
      #pragma unroll
      for (int i = 0; i < 4; ++i) {
        #pragma unroll
        for (int j = 0; j < 4; ++j)
          acc[i][j] = __builtin_amdgcn_mfma_f32_16x16x32_bf16(af[i], bfv[j], acc[i][j], 0, 0, 0);
      }
    }
  }
  const int rq = lq * 4;
  #pragma unroll
  for (int j = 0; j < 4; ++j) {
    const long col = n0 + wn * 64 + j * 16 + lr;
    const float bv = (EPI >= 1) ? bf2f(bias[col]) : 0.f;
    #pragma unroll
    for (int i = 0; i < 4; ++i) {
      const long row0 = m0 + wm * 64 + i * 16 + rq;
      #pragma unroll
      for (int q = 0; q < 4; ++q) {
        const long row = row0 + q;
        float v = acc[i][j][q] + bv;
        if (EPI == 2) v = gelu_exact(v);
        if (EPI == 3) v += bf2f(resid[row * (long)ldc + col]);
        if (COUT) stv(Cg, row * (long)ldc + col, v, isf);
        else ((u16*)Cg)[row * (long)ldc + col] = f2bf(v);
      }
    }
  }
}

// ---------------------------------------------------------------------------
// Fused attention (unchanged, passing)
// ---------------------------------------------------------------------------
__global__ __launch_bounds__(256)
void attn_fused(const u16* __restrict__ qkv, u16* __restrict__ ctx) {
  const int z = blockIdx.y, bb = z >> 2, hh = z & 3;
  const int w = threadIdx.x >> 6, lane = threadIdx.x & 63;
  const int tid = threadIdx.x;
  const long t0 = (long)blockIdx.x * 64;
  __shared__ __align__(16) u16 P1[10240];
  __shared__ __align__(16) u16 Pl[64 * 264];
  __shared__ __align__(16) u16 Vt[256 * 40];
  const u16* qb = qkv + (long)bb * T_ * 3 * E_ + hh * HD_;
  const u16* kb = qb + E_;
  const u16* vb = qb + 2 * E_;
  const int rr = lane >> 2, cc = lane & 3;
  const int lr = lane & 15, lq = lane >> 4, lk = lq * 8;
  f32x4 acc[16] = {};
  for (int kt = 0; kt < 8; ++kt) {
    const int k0 = kt * 32;
    __syncthreads();
    gld16((char*)P1 + w * 16 * 64, qb + (t0 + w * 16 + rr) * (3L * E_) + k0 + cc * 8);
    #pragma unroll
    for (int c = 0; c < 4; ++c) {
      const int rb = w * 64 + c * 16;
      gld16((char*)P1 + 4096 + rb * 64, kb + (long)(rb + rr) * (3L * E_) + k0 + cc * 8);
    }
    __syncthreads();
    bf16x8 aq = *(const bf16x8*)&P1[(w * 16 + lr) * 32 + lk];
    #pragma unroll
    for (int nt = 0; nt < 16; ++nt) {
      bf16x8 bk = *(const bf16x8*)&P1[2048 + (nt * 16 + lr) * 32 + lk];
      acc[nt] = __builtin_amdgcn_mfma_f32_16x16x32_bf16(aq, bk, acc[nt], 0, 0, 0);
    }
  }
  #pragma unroll
  for (int q = 0; q < 4; ++q) {
    float mx = -3.4e38f;
    #pragma unroll
    for (int nt = 0; nt < 16; ++nt) mx = fmaxf(mx, acc[nt][q]);
    mx = fmaxf(mx, __shfl_xor(mx, 1));
    mx = fmaxf(mx, __shfl_xor(mx, 2));
    mx = fmaxf(mx, __shfl_xor(mx, 4));
    mx = fmaxf(mx, __shfl_xor(mx, 8));
    float e[16], sum = 0.f;
    #pragma unroll
    for (int nt = 0; nt < 16; ++nt) {
      e[nt] = __expf((acc[nt][q] - mx) * 0.0625f);
      sum += e[nt];
    }
    sum += __shfl_xor(sum, 1);
    sum += __shfl_xor(sum, 2);
    sum += __shfl_xor(sum, 4);
    sum += __shfl_xor(sum, 8);
    const float inv = 1.f / sum;
    const int rowl = w * 16 + lq * 4 + q;
    #pragma unroll
    for (int nt = 0; nt < 16; ++nt)
      Pl[rowl * 264 + nt * 16 + lr] = f2bf(e[nt] * inv);
  }
  f32x4 acc2[16] = {};
  for (int st = 0; st < 8; ++st) {
    const int s0 = st * 32;
    __syncthreads();
    #pragma unroll
    for (int c = 0; c < 4; ++c) {
      const int rb = w * 8 + c * 2;
      gld16((char*)P1 + rb * 512, vb + (s0 + rb + (lane >> 5)) * (3L * E_) + (lane & 31) * 8);
    }
    __syncthreads();
    u16 col[32];
    #pragma unroll
    for (int si = 0; si < 32; ++si) col[si] = P1[si * 256 + tid];
    #pragma unroll
    for (int cq = 0; cq < 4; ++cq)
      *(uint4*)&Vt[tid * 40 + cq * 8] = *(const uint4*)&col[cq * 8];
    __syncthreads();
    bf16x8 pa = *(const bf16x8*)&Pl[(w * 16 + lr) * 264 + s0 + lk];
    #pragma unroll
    for (int nt = 0; nt < 16; ++nt) {
      bf16x8 bv = *(const bf16x8*)&Vt[(nt * 16 + lr) * 40 + lk];
      acc2[nt] = __builtin_amdgcn_mfma_f32_16x16x32_bf16(pa, bv, acc2[nt], 0, 0, 0);
    }
  }
  const int rq = lq * 4;
  #pragma unroll
  for (int nt = 0; nt < 16; ++nt) {
    const int cold = nt * 16 + lr;
    #pragma unroll
    for (int q = 0; q < 4; ++q) {
      const long row = t0 + w * 16 + rq + q;
      ctx[((long)bb * T_ + row) * E_ + hh * HD_ + cold] = f2bf(acc2[nt][q]);
    }
  }
}

// ---------------------------------------------------------------------------
extern "C" void kernel_launch(void* const* d_in, const int* in_sizes, int n_in,
                              void* d_out, int out_size, void* d_ws, size_t ws_size,
                              hipStream_t stream) {
  (void)in_sizes; (void)n_in; (void)out_size; (void)ws_size;
  char* ws = (char*)d_ws;
  // ws layout (bytes), peak 151MB (proven safe: round 2 wrote 165.7MB cleanly)
  u16* BIASA = (u16*)(ws + 0);
  u32* FLAG  = (u32*)(ws + 12288);
  u16* wtI   = (u16*)(ws + 65536);      // [3072][1024]
  u16* wtM   = (u16*)(ws + 6356992);    // [1024][1024]
  u16* wtO   = (u16*)(ws + 8454144);    // [256][1024]
  u16* wtF1  = (u16*)(ws + 8978432);    // [512][256]
  u16* wtF2  = (u16*)(ws + 9240576);    // [256][512]
  u16* XG    = (u16*)(ws + 9502720);    // [B,T,F]
  u16* GRUO  = (u16*)(ws + 16777216);   // [B,T,E] (dead after QKV gemm)
  u16* CTX   = GRUO;                    // [B,T,E] overlay
  u16* QKV   = (u16*)(ws + 50331648);   // [B,T,3E] (dead after attn)
  u16* MHA   = (u16*)(ws + 50331648);   // [B,T,E] overlay on dead QKV
  u16* H1    = (u16*)(ws + 83886080);   // [B,T,D]
  u16* FFH   = (u16*)(ws + 92274688);   // [B,T,2D]

  detect_dtype<<<1, 64, 0, stream>>>((const u16*)d_in[0], FLAG);

  convert_in<<<12, 256, 0, stream>>>(d_in[10], BIASA + 0,    3072, FLAG);
  convert_in<<<4,  256, 0, stream>>>(d_in[12], BIASA + 3072, 1024, FLAG);
  convert_in<<<1,  256, 0, stream>>>(d_in[14], BIASA + 4096, 256,  FLAG);
  convert_in<<<2,  256, 0, stream>>>(d_in[16], BIASA + 4352, 512,  FLAG);
  convert_in<<<1,  256, 0, stream>>>(d_in[18], BIASA + 4864, 256,  FLAG);

  dim3 tb(32, 8);
  transpose_cvt<<<dim3(3072 / 32, 1024 / 32), tb, 0, stream>>>(d_in[9],  wtI,  1024, 3072, FLAG);
  transpose_cvt<<<dim3(1024 / 32, 1024 / 32), tb, 0, stream>>>(d_in[11], wtM,  1024, 1024, FLAG);
  transpose_cvt<<<dim3(256 / 32, 1024 / 32),  tb, 0, stream>>>(d_in[13], wtO,  1024, 256,  FLAG);
  transpose_cvt<<<dim3(512 / 32, 256 / 32),   tb, 0, stream>>>(d_in[15], wtF1, 256,  512,  FLAG);
  transpose_cvt<<<dim3(256 / 32, 512 / 32),   tb, 0, stream>>>(d_in[17], wtF2, 512,  256,  FLAG);

  input_mlp2<<<B_ * T_, 128, 0, stream>>>(d_in[0], d_in[1], d_in[2], d_in[3], d_in[4],
                                          FLAG, XG, d_out);
  gru_scan4<<<256, 256, 0, stream>>>(XG, d_in[5], d_in[6], d_in[7], d_in[8], FLAG, GRUO);

  // qkv = gruo @ in_proj + b   (M=16384, N=3072, K=1024) -- 8-phase 256^2
  gemm8p<<<dim3(64 * 12), 512, 0, stream>>>(GRUO, 1024, wtI, 1024,
      QKV, 3072, BIASA, 1024, 64, 64 * 12);
  // fused attention -> CTX [B,T,E]
  attn_fused<<<dim3(4, B_ * NH_), 256, 0, stream>>>(QKV, CTX);
  // mha = ctx @ mha_out_w + b  (M=16384, N=1024, K=1024) -- 8-phase 256^2
  gemm8p<<<dim3(64 * 4), 512, 0, stream>>>(CTX, 1024, wtM, 1024,
      MHA, 1024, BIASA + 3072, 1024, 64, 64 * 4);
  // h1 = mha @ outp_w + b  (M=16384, N=256, K=1024)
  gemm_bt<1, 0><<<dim3(128 * 2, 1), 256, 0, stream>>>(MHA, 1024, wtO, 1024,
      H1, 256, BIASA + 4096, nullptr, 1024, 128, FLAG);
  // ffh = gelu(h1 @ ffn_w1 + b)  (M=16384, N=512, K=256)
  gemm_bt<2, 0><<<dim3(128 * 4, 1), 256, 0, stream>>>(H1, 256, wtF1, 256,
      FFH, 512, BIASA + 4352, nullptr, 256, 128, FLAG);
  // y = h1 + ffh @ ffn_w2 + b  (M=16384, N=256, K=512) -> final output
  gemm_bt<3, 1><<<dim3(128 * 2, 1), 256, 0, stream>>>(FFH, 512, wtF2, 512,
      d_out, 256, BIASA + 4864, H1, 512, 128, FLAG);
}

// Round 10
// 461.338 us; speedup vs baseline: 1.0720x; 1.0720x over previous
//
#include <hip/hip_runtime.h>
#include <hip/hip_bf16.h>
#include <math.h>

// Problem dims
#define B_  64
#define T_  256
#define F_  128
#define H_  8
#define E_  1024   // F*H
#define NH_ 4
#define HD_ 256    // E/NH
#define D_  256

// output element offsets within d_out (element units of the storage dtype)
#define OFF_Y_  0L
#define OFF_FI_ 4194304L
#define OFF_IA_ 4210688L

typedef unsigned short u16;
typedef unsigned int   u32;
typedef short bf16x8 __attribute__((ext_vector_type(8)));
typedef float f32x4  __attribute__((ext_vector_type(4)));

__device__ __forceinline__ float bf2f(u16 u) {
  union { u32 u; float f; } x; x.u = ((u32)u) << 16; return x.f;
}
__device__ __forceinline__ u16 f2bf(float f) {
  union { float f; u32 u; } x; x.f = f;
  u32 r = (x.u + 0x7fffu + ((x.u >> 16) & 1u)) >> 16;
  return (u16)r;
}
__device__ __forceinline__ float gelu_exact(float v) {
  return 0.5f * v * (1.f + erff(v * 0.70710678118654752f));
}
__device__ __forceinline__ float sigmoidf_(float v) {
  return 1.f / (1.f + __expf(-v));
}
__device__ __forceinline__ float ldv(const void* p, long i, bool isf) {
  return isf ? ((const float*)p)[i] : bf2f(((const u16*)p)[i]);
}
__device__ __forceinline__ void stv(void* p, long i, float v, bool isf) {
  if (isf) ((float*)p)[i] = v;
  else ((u16*)p)[i] = f2bf(v);
}
// async global->LDS, 16B/lane: LDS dest = wave-uniform base + lane*16 (HW)
__device__ __forceinline__ void gld16(void* lds, const void* g) {
  __builtin_amdgcn_global_load_lds(
      (const __attribute__((address_space(1))) u32*)g,
      (__attribute__((address_space(3))) u32*)lds, 16, 0, 0);
}

// ---------------------------------------------------------------------------
// dtype detector (flag: 0 = bf16 storage, 1 = f32 storage)
// ---------------------------------------------------------------------------
__global__ void detect_dtype(const u16* __restrict__ x, u32* __restrict__ flag) {
  if (threadIdx.x == 0 && blockIdx.x == 0) {
    int good = 0;
    for (int i = 0; i < 512; ++i) {
      u16 v = x[i];
      int e = (v >> 7) & 0xFF;
      if (v == 0 || (e >= 100 && e <= 140)) ++good;
    }
    *flag = (good >= 450) ? 0u : 1u;
  }
}

__global__ __launch_bounds__(256)
void convert_in(const void* __restrict__ src, u16* __restrict__ dst, int n,
                const u32* __restrict__ flag) {
  const bool isf = (*flag != 0);
  int i = blockIdx.x * 256 + threadIdx.x;
  if (i < n) dst[i] = isf ? f2bf(((const float*)src)[i]) : ((const u16*)src)[i];
}

// fused transpose + convert: out[c][r] (bf16) = in[r][c] (raw). dims %32 == 0
__global__ void transpose_cvt(const void* __restrict__ in, u16* __restrict__ out,
                              int R, int C, const u32* __restrict__ flag) {
  const bool isf = (*flag != 0);
  __shared__ float t[32][33];
  const int c0 = blockIdx.x * 32, r0 = blockIdx.y * 32;
  const int tx = threadIdx.x, ty = threadIdx.y;
  for (int i = ty; i < 32; i += 8)
    t[i][tx] = ldv(in, (long)(r0 + i) * C + c0 + tx, isf);
  __syncthreads();
  for (int i = ty; i < 32; i += 8)
    out[(long)(c0 + i) * R + r0 + tx] = f2bf(t[tx][i]);
}

// ---------------------------------------------------------------------------
// K1: input-attention MLP (unchanged, passing)
// ---------------------------------------------------------------------------
__global__ __launch_bounds__(128)
void input_mlp2(const void* __restrict__ x,
                const void* __restrict__ w1, const void* __restrict__ b1,
                const void* __restrict__ w2, const void* __restrict__ b2,
                const u32* __restrict__ flag,
                u16* __restrict__ xg, void* __restrict__ dout) {
  const bool isf = (*flag != 0);
  const long row = blockIdx.x;
  const int tid = threadIdx.x;
  __shared__ float xr[F_];
  __shared__ float hid[32];
  __shared__ float red[2];
  float xv = ldv(x, row * F_ + tid, isf);
  xr[tid] = xv;
  __syncthreads();
  if (tid < 32) {
    float s = ldv(b1, tid, isf);
    for (int f = 0; f < F_; ++f) s += xr[f] * ldv(w1, f * 32 + tid, isf);
    hid[tid] = gelu_exact(s);
  }
  __syncthreads();
  float s = ldv(b2, tid, isf);
  #pragma unroll 8
  for (int j = 0; j < 32; ++j) s += hid[j] * ldv(w2, j * F_ + tid, isf);
  float ia = sigmoidf_(s);
  stv(dout, OFF_IA_ + row * F_ + tid, ia, isf);
  xg[row * F_ + tid] = f2bf(ia * xv);
  float v = ia;
  for (int o = 32; o > 0; o >>= 1) v += __shfl_down(v, o);
  if ((tid & 63) == 0) red[tid >> 6] = v;
  __syncthreads();
  if (tid == 0) stv(dout, OFF_FI_ + row, red[0] + red[1], isf);
}

// ---------------------------------------------------------------------------
// K2 v4: GRU bank (unchanged, passing)
// ---------------------------------------------------------------------------
__global__ __launch_bounds__(256)
void gru_scan4(const u16* __restrict__ xg, const void* __restrict__ W_ih,
               const void* __restrict__ W_hh, const void* __restrict__ b_ih,
               const void* __restrict__ b_hh, const u32* __restrict__ flag,
               u16* __restrict__ gruo) {
  const bool isf = (*flag != 0);
  const int tid = threadIdx.x;
  const int ric = tid >> 3;
  const int j   = tid & 7;
  const int rec = blockIdx.x * 32 + ric;
  const int b = rec >> 7, f = rec & 127;
  __shared__ __align__(16) float hbuf[32][8];
  float whr[8], whz[8], whn[8];
  #pragma unroll
  for (int k = 0; k < 8; ++k) {
    whr[k] = ldv(W_hh, (long)f * 192 + j * 8 + k, isf);
    whz[k] = ldv(W_hh, (long)f * 192 + (8 + j) * 8 + k, isf);
    whn[k] = ldv(W_hh, (long)f * 192 + (16 + j) * 8 + k, isf);
  }
  const float wir = ldv(W_ih, f * 24 + j, isf);
  const float wiz = ldv(W_ih, f * 24 + 8 + j, isf);
  const float win = ldv(W_ih, f * 24 + 16 + j, isf);
  const float cbr = ldv(b_ih, f * 24 + j, isf) + ldv(b_hh, f * 24 + j, isf);
  const float cbz = ldv(b_ih, f * 24 + 8 + j, isf) + ldv(b_hh, f * 24 + 8 + j, isf);
  const float bin_ = ldv(b_ih, f * 24 + 16 + j, isf);
  const float bhn_ = ldv(b_hh, f * 24 + 16 + j, isf);
  float h[8];
  #pragma unroll
  for (int k = 0; k < 8; ++k) h[k] = 0.f;
  const u16* xp = xg + (long)b * T_ * F_ + f;
  u16* op = gruo + (long)b * T_ * E_ + f * 8 + j;
  float xv = bf2f(xp[0]);
  for (int t = 0; t < T_; ++t) {
    float xn = (t + 1 < T_) ? bf2f(xp[(t + 1) * F_]) : 0.f;
    float ar = fmaf(xv, wir, cbr);
    float az = fmaf(xv, wiz, cbz);
    float an = bhn_;
    #pragma unroll
    for (int k = 0; k < 8; ++k) {
      ar = fmaf(h[k], whr[k], ar);
      az = fmaf(h[k], whz[k], az);
      an = fmaf(h[k], whn[k], an);
    }
    const float r = sigmoidf_(ar);
    const float z = sigmoidf_(az);
    const float a = fmaf(r, an, fmaf(xv, win, bin_));
    const float e = __expf(2.f * a);
    const float n = 1.f - 2.f / (e + 1.f);
    const float hn = fmaf(z, h[j] - n, n);
    op[(long)t * E_] = f2bf(hn);
    hbuf[ric][j] = hn;
    f32x4 h0 = *(const f32x4*)&hbuf[ric][0];
    f32x4 h1 = *(const f32x4*)&hbuf[ric][4];
    h[0] = h0[0]; h[1] = h0[1]; h[2] = h0[2]; h[3] = h0[3];
    h[4] = h1[0]; h[5] = h1[1]; h[6] = h1[2]; h[7] = h1[3];
    xv = xn;
  }
}

// ---------------------------------------------------------------------------
// bt-form MFMA GEMM v3: 128x128, BK=64, swizzled gld16 staging (round-8 core).
// NEW: bn-FASTEST block order + m204 bijective XCD chunking, so each XCD's
// co-resident blocks share a small set of A-panels (fits per-XCD L2) and
// stream the small B matrix. A is HBM-fetched ~once.
// EPI: 0=none, 1=+bias, 2=+bias+gelu, 3=+bias+resid. COUT: dtype-flagged y.
// ---------------------------------------------------------------------------
template <int EPI, int COUT>
__global__ __launch_bounds__(256)
void gemm_bt(const u16* __restrict__ A, int lda,
             const u16* __restrict__ Bp, int ldb,
             void* __restrict__ Cg, int ldc,
             const u16* __restrict__ bias, const u16* __restrict__ resid,
             int K, int nbn, const u32* __restrict__ flag) {
  const bool isf = (*flag != 0);
  // m204 bijective XCD remap, then bn-fastest
  const int nwg = gridDim.x;
  const int q8 = nwg >> 3, r8 = nwg & 7;
  const int xcd = blockIdx.x & 7, off = blockIdx.x >> 3;
  const int wg = (xcd < r8) ? xcd * (q8 + 1) + off
                            : r8 * (q8 + 1) + (xcd - r8) * q8 + off;
  const int bn = wg % nbn, bm = wg / nbn;
  const int w = threadIdx.x >> 6, lane = threadIdx.x & 63;
  __shared__ __align__(16) u16 As[128 * 64];
  __shared__ __align__(16) u16 Bs[128 * 64];
  const long m0 = (long)bm * 128, n0 = (long)bn * 128;
  const int wm = w >> 1, wn = w & 1;
  const int lr8 = lane >> 3;
  const int csw = ((lane & 7) ^ (lr8 & 7)) * 8;
  f32x4 acc[4][4] = {};
  const int nk = K >> 6;
  const int lr = lane & 15, lq = lane >> 4;
  for (int kt = 0; kt < nk; ++kt) {
    const int k0 = kt << 6;
    __syncthreads();
    #pragma unroll
    for (int c = 0; c < 4; ++c) {
      const int rb = w * 32 + c * 8;
      gld16((char*)As + rb * 128, A + (m0 + rb + lr8) * (long)lda + k0 + csw);
      gld16((char*)Bs + rb * 128, Bp + (n0 + rb + lr8) * (long)ldb + k0 + csw);
    }
    __syncthreads();
    #pragma unroll
    for (int sub = 0; sub < 2; ++sub) {
      const int ch = sub * 4 + lq;
      const int cof = ((ch ^ (lr & 7)) << 3);
      bf16x8 af[4], bfv[4];
      #pragma unroll
      for (int i = 0; i < 4; ++i)
        af[i] = *(const bf16x8*)&As[(wm * 64 + i * 16 + lr) * 64 + cof];
      #pragma unroll
      for (int i = 0; i < 4; ++i)
        bfv[i] = *(const bf16x8*)&Bs[(wn * 64 + i * 16 + lr) * 64 + cof];
      #pragma unroll
      for (int i = 0; i < 4; ++i) {
        #pragma unroll
        for (int j = 0; j < 4; ++j)
          acc[i][j] = __builtin_amdgcn_mfma_f32_16x16x32_bf16(af[i], bfv[j], acc[i][j], 0, 0, 0);
      }
    }
  }
  const int rq = lq * 4;
  #pragma unroll
  for (int j = 0; j < 4; ++j) {
    const long col = n0 + wn * 64 + j * 16 + lr;
    const float bv = (EPI >= 1) ? bf2f(bias[col]) : 0.f;
    #pragma unroll
    for (int i = 0; i < 4; ++i) {
      const long row0 = m0 + wm * 64 + i * 16 + rq;
      #pragma unroll
      for (int q = 0; q < 4; ++q) {
        const long row = row0 + q;
        float v = acc[i][j][q] + bv;
        if (EPI == 2) v = gelu_exact(v);
        if (EPI == 3) v += bf2f(resid[row * (long)ldc + col]);
        if (COUT) stv(Cg, row * (long)ldc + col, v, isf);
        else ((u16*)Cg)[row * (long)ldc + col] = f2bf(v);
      }
    }
  }
}

// ---------------------------------------------------------------------------
// Fused attention (unchanged, passing)
// ---------------------------------------------------------------------------
__global__ __launch_bounds__(256)
void attn_fused(const u16* __restrict__ qkv, u16* __restrict__ ctx) {
  const int z = blockIdx.y, bb = z >> 2, hh = z & 3;
  const int w = threadIdx.x >> 6, lane = threadIdx.x & 63;
  const int tid = threadIdx.x;
  const long t0 = (long)blockIdx.x * 64;
  __shared__ __align__(16) u16 P1[10240];
  __shared__ __align__(16) u16 Pl[64 * 264];
  __shared__ __align__(16) u16 Vt[256 * 40];
  const u16* qb = qkv + (long)bb * T_ * 3 * E_ + hh * HD_;
  const u16* kb = qb + E_;
  const u16* vb = qb + 2 * E_;
  const int rr = lane >> 2, cc = lane & 3;
  const int lr = lane & 15, lq = lane >> 4, lk = lq * 8;
  f32x4 acc[16] = {};
  for (int kt = 0; kt < 8; ++kt) {
    const int k0 = kt * 32;
    __syncthreads();
    gld16((char*)P1 + w * 16 * 64, qb + (t0 + w * 16 + rr) * (3L * E_) + k0 + cc * 8);
    #pragma unroll
    for (int c = 0; c < 4; ++c) {
      const int rb = w * 64 + c * 16;
      gld16((char*)P1 + 4096 + rb * 64, kb + (long)(rb + rr) * (3L * E_) + k0 + cc * 8);
    }
    __syncthreads();
    bf16x8 aq = *(const bf16x8*)&P1[(w * 16 + lr) * 32 + lk];
    #pragma unroll
    for (int nt = 0; nt < 16; ++nt) {
      bf16x8 bk = *(const bf16x8*)&P1[2048 + (nt * 16 + lr) * 32 + lk];
      acc[nt] = __builtin_amdgcn_mfma_f32_16x16x32_bf16(aq, bk, acc[nt], 0, 0, 0);
    }
  }
  #pragma unroll
  for (int q = 0; q < 4; ++q) {
    float mx = -3.4e38f;
    #pragma unroll
    for (int nt = 0; nt < 16; ++nt) mx = fmaxf(mx, acc[nt][q]);
    mx = fmaxf(mx, __shfl_xor(mx, 1));
    mx = fmaxf(mx, __shfl_xor(mx, 2));
    mx = fmaxf(mx, __shfl_xor(mx, 4));
    mx = fmaxf(mx, __shfl_xor(mx, 8));
    float e[16], sum = 0.f;
    #pragma unroll
    for (int nt = 0; nt < 16; ++nt) {
      e[nt] = __expf((acc[nt][q] - mx) * 0.0625f);
      sum += e[nt];
    }
    sum += __shfl_xor(sum, 1);
    sum += __shfl_xor(sum, 2);
    sum += __shfl_xor(sum, 4);
    sum += __shfl_xor(sum, 8);
    const float inv = 1.f / sum;
    const int rowl = w * 16 + lq * 4 + q;
    #pragma unroll
    for (int nt = 0; nt < 16; ++nt)
      Pl[rowl * 264 + nt * 16 + lr] = f2bf(e[nt] * inv);
  }
  f32x4 acc2[16] = {};
  for (int st = 0; st < 8; ++st) {
    const int s0 = st * 32;
    __syncthreads();
    #pragma unroll
    for (int c = 0; c < 4; ++c) {
      const int rb = w * 8 + c * 2;
      gld16((char*)P1 + rb * 512, vb + (s0 + rb + (lane >> 5)) * (3L * E_) + (lane & 31) * 8);
    }
    __syncthreads();
    u16 col[32];
    #pragma unroll
    for (int si = 0; si < 32; ++si) col[si] = P1[si * 256 + tid];
    #pragma unroll
    for (int cq = 0; cq < 4; ++cq)
      *(uint4*)&Vt[tid * 40 + cq * 8] = *(const uint4*)&col[cq * 8];
    __syncthreads();
    bf16x8 pa = *(const bf16x8*)&Pl[(w * 16 + lr) * 264 + s0 + lk];
    #pragma unroll
    for (int nt = 0; nt < 16; ++nt) {
      bf16x8 bv = *(const bf16x8*)&Vt[(nt * 16 + lr) * 40 + lk];
      acc2[nt] = __builtin_amdgcn_mfma_f32_16x16x32_bf16(pa, bv, acc2[nt], 0, 0, 0);
    }
  }
  const int rq = lq * 4;
  #pragma unroll
  for (int nt = 0; nt < 16; ++nt) {
    const int cold = nt * 16 + lr;
    #pragma unroll
    for (int q = 0; q < 4; ++q) {
      const long row = t0 + w * 16 + rq + q;
      ctx[((long)bb * T_ + row) * E_ + hh * HD_ + cold] = f2bf(acc2[nt][q]);
    }
  }
}

// ---------------------------------------------------------------------------
extern "C" void kernel_launch(void* const* d_in, const int* in_sizes, int n_in,
                              void* d_out, int out_size, void* d_ws, size_t ws_size,
                              hipStream_t stream) {
  (void)in_sizes; (void)n_in; (void)out_size; (void)ws_size;
  char* ws = (char*)d_ws;
  // ws layout (bytes), peak 151MB (proven safe: round 2 wrote 165.7MB cleanly)
  u16* BIASA = (u16*)(ws + 0);
  u32* FLAG  = (u32*)(ws + 12288);
  u16* wtI   = (u16*)(ws + 65536);      // [3072][1024]
  u16* wtM   = (u16*)(ws + 6356992);    // [1024][1024]
  u16* wtO   = (u16*)(ws + 8454144);    // [256][1024]
  u16* wtF1  = (u16*)(ws + 8978432);    // [512][256]
  u16* wtF2  = (u16*)(ws + 9240576);    // [256][512]
  u16* XG    = (u16*)(ws + 9502720);    // [B,T,F]
  u16* GRUO  = (u16*)(ws + 16777216);   // [B,T,E] (dead after QKV gemm)
  u16* CTX   = GRUO;                    // [B,T,E] overlay
  u16* QKV   = (u16*)(ws + 50331648);   // [B,T,3E] (dead after attn)
  u16* MHA   = (u16*)(ws + 50331648);   // [B,T,E] overlay on dead QKV
  u16* H1    = (u16*)(ws + 83886080);   // [B,T,D]
  u16* FFH   = (u16*)(ws + 92274688);   // [B,T,2D]

  detect_dtype<<<1, 64, 0, stream>>>((const u16*)d_in[0], FLAG);

  convert_in<<<12, 256, 0, stream>>>(d_in[10], BIASA + 0,    3072, FLAG);
  convert_in<<<4,  256, 0, stream>>>(d_in[12], BIASA + 3072, 1024, FLAG);
  convert_in<<<1,  256, 0, stream>>>(d_in[14], BIASA + 4096, 256,  FLAG);
  convert_in<<<2,  256, 0, stream>>>(d_in[16], BIASA + 4352, 512,  FLAG);
  convert_in<<<1,  256, 0, stream>>>(d_in[18], BIASA + 4864, 256,  FLAG);

  dim3 tb(32, 8);
  transpose_cvt<<<dim3(3072 / 32, 1024 / 32), tb, 0, stream>>>(d_in[9],  wtI,  1024, 3072, FLAG);
  transpose_cvt<<<dim3(1024 / 32, 1024 / 32), tb, 0, stream>>>(d_in[11], wtM,  1024, 1024, FLAG);
  transpose_cvt<<<dim3(256 / 32, 1024 / 32),  tb, 0, stream>>>(d_in[13], wtO,  1024, 256,  FLAG);
  transpose_cvt<<<dim3(512 / 32, 256 / 32),   tb, 0, stream>>>(d_in[15], wtF1, 256,  512,  FLAG);
  transpose_cvt<<<dim3(256 / 32, 512 / 32),   tb, 0, stream>>>(d_in[17], wtF2, 512,  256,  FLAG);

  input_mlp2<<<B_ * T_, 128, 0, stream>>>(d_in[0], d_in[1], d_in[2], d_in[3], d_in[4],
                                          FLAG, XG, d_out);
  gru_scan4<<<256, 256, 0, stream>>>(XG, d_in[5], d_in[6], d_in[7], d_in[8], FLAG, GRUO);

  // qkv = gruo @ in_proj + b   (M=16384, N=3072, K=1024); nbn = 24
  gemm_bt<1, 0><<<dim3(128 * 24, 1), 256, 0, stream>>>(GRUO, 1024, wtI, 1024,
      QKV, 3072, BIASA, nullptr, 1024, 24, FLAG);
  // fused attention -> CTX [B,T,E]
  attn_fused<<<dim3(4, B_ * NH_), 256, 0, stream>>>(QKV, CTX);
  // mha = ctx @ mha_out_w + b  (M=16384, N=1024, K=1024); nbn = 8
  gemm_bt<1, 0><<<dim3(128 * 8, 1), 256, 0, stream>>>(CTX, 1024, wtM, 1024,
      MHA, 1024, BIASA + 3072, nullptr, 1024, 8, FLAG);
  // h1 = mha @ outp_w + b  (M=16384, N=256, K=1024); nbn = 2
  gemm_bt<1, 0><<<dim3(128 * 2, 1), 256, 0, stream>>>(MHA, 1024, wtO, 1024,
      H1, 256, BIASA + 4096, nullptr, 1024, 2, FLAG);
  // ffh = gelu(h1 @ ffn_w1 + b)  (M=16384, N=512, K=256); nbn = 4
  gemm_bt<2, 0><<<dim3(128 * 4, 1), 256, 0, stream>>>(H1, 256, wtF1, 256,
      FFH, 512, BIASA + 4352, nullptr, 256, 4, FLAG);
  // y = h1 + ffh @ ffn_w2 + b  (M=16384, N=256, K=512) -> final output; nbn = 2
  gemm_bt<3, 1><<<dim3(128 * 2, 1), 256, 0, stream>>>(FFH, 512, wtF2, 512,
      d_out, 256, BIASA + 4864, H1, 512, 2, FLAG);
}

// Round 11
// 447.923 us; speedup vs baseline: 1.1041x; 1.0299x over previous
//
#include <hip/hip_runtime.h>
#include <hip/hip_bf16.h>
#include <math.h>

// Problem dims
#define B_  64
#define T_  256
#define F_  128
#define H_  8
#define E_  1024   // F*H
#define NH_ 4
#define HD_ 256    // E/NH
#define D_  256

// output element offsets within d_out (element units of the storage dtype)
#define OFF_Y_  0L
#define OFF_FI_ 4194304L
#define OFF_IA_ 4210688L

typedef unsigned short u16;
typedef unsigned int   u32;
typedef short bf16x8 __attribute__((ext_vector_type(8)));
typedef float f32x4  __attribute__((ext_vector_type(4)));

__device__ __forceinline__ float bf2f(u16 u) {
  union { u32 u; float f; } x; x.u = ((u32)u) << 16; return x.f;
}
__device__ __forceinline__ u16 f2bf(float f) {
  union { float f; u32 u; } x; x.f = f;
  u32 r = (x.u + 0x7fffu + ((x.u >> 16) & 1u)) >> 16;
  return (u16)r;
}
__device__ __forceinline__ float gelu_exact(float v) {
  return 0.5f * v * (1.f + erff(v * 0.70710678118654752f));
}
__device__ __forceinline__ float sigmoidf_(float v) {
  return 1.f / (1.f + __expf(-v));
}
__device__ __forceinline__ float ldv(const void* p, long i, bool isf) {
  return isf ? ((const float*)p)[i] : bf2f(((const u16*)p)[i]);
}
__device__ __forceinline__ void stv(void* p, long i, float v, bool isf) {
  if (isf) ((float*)p)[i] = v;
  else ((u16*)p)[i] = f2bf(v);
}
// async global->LDS, 16B/lane: LDS dest = wave-uniform base + lane*16 (HW)
__device__ __forceinline__ void gld16(void* lds, const void* g) {
  __builtin_amdgcn_global_load_lds(
      (const __attribute__((address_space(1))) u32*)g,
      (__attribute__((address_space(3))) u32*)lds, 16, 0, 0);
}

// ---------------------------------------------------------------------------
// dtype detector (flag: 0 = bf16 storage, 1 = f32 storage)
// ---------------------------------------------------------------------------
__global__ void detect_dtype(const u16* __restrict__ x, u32* __restrict__ flag) {
  if (threadIdx.x == 0 && blockIdx.x == 0) {
    int good = 0;
    for (int i = 0; i < 512; ++i) {
      u16 v = x[i];
      int e = (v >> 7) & 0xFF;
      if (v == 0 || (e >= 100 && e <= 140)) ++good;
    }
    *flag = (good >= 450) ? 0u : 1u;
  }
}

__global__ __launch_bounds__(256)
void convert_in(const void* __restrict__ src, u16* __restrict__ dst, int n,
                const u32* __restrict__ flag) {
  const bool isf = (*flag != 0);
  int i = blockIdx.x * 256 + threadIdx.x;
  if (i < n) dst[i] = isf ? f2bf(((const float*)src)[i]) : ((const u16*)src)[i];
}

// fused transpose + convert: out[c][r] (bf16) = in[r][c] (raw). dims %32 == 0
__global__ void transpose_cvt(const void* __restrict__ in, u16* __restrict__ out,
                              int R, int C, const u32* __restrict__ flag) {
  const bool isf = (*flag != 0);
  __shared__ float t[32][33];
  const int c0 = blockIdx.x * 32, r0 = blockIdx.y * 32;
  const int tx = threadIdx.x, ty = threadIdx.y;
  for (int i = ty; i < 32; i += 8)
    t[i][tx] = ldv(in, (long)(r0 + i) * C + c0 + tx, isf);
  __syncthreads();
  for (int i = ty; i < 32; i += 8)
    out[(long)(c0 + i) * R + r0 + tx] = f2bf(t[tx][i]);
}

// ---------------------------------------------------------------------------
// K1: input-attention MLP. v2: w1 phase uses all 128 lanes (quarter partials).
// ---------------------------------------------------------------------------
__global__ __launch_bounds__(128)
void input_mlp2(const void* __restrict__ x,
                const void* __restrict__ w1, const void* __restrict__ b1,
                const void* __restrict__ w2, const void* __restrict__ b2,
                const u32* __restrict__ flag,
                u16* __restrict__ xg, void* __restrict__ dout) {
  const bool isf = (*flag != 0);
  const long row = blockIdx.x;
  const int tid = threadIdx.x;
  __shared__ float xr[F_];
  __shared__ float hid4[4][32];
  __shared__ float hid[32];
  __shared__ float red[2];
  float xv = ldv(x, row * F_ + tid, isf);
  xr[tid] = xv;
  __syncthreads();
  {
    const int g = tid & 31, part = tid >> 5;
    const int f0 = part * 32;
    float s = 0.f;
    #pragma unroll 8
    for (int f = 0; f < 32; ++f) s += xr[f0 + f] * ldv(w1, (long)(f0 + f) * 32 + g, isf);
    hid4[part][g] = s;
  }
  __syncthreads();
  if (tid < 32)
    hid[tid] = gelu_exact(ldv(b1, tid, isf) + hid4[0][tid] + hid4[1][tid]
                          + hid4[2][tid] + hid4[3][tid]);
  __syncthreads();
  float s = ldv(b2, tid, isf);
  #pragma unroll 8
  for (int j = 0; j < 32; ++j) s += hid[j] * ldv(w2, j * F_ + tid, isf);
  float ia = sigmoidf_(s);
  stv(dout, OFF_IA_ + row * F_ + tid, ia, isf);
  xg[row * F_ + tid] = f2bf(ia * xv);
  float v = ia;
  for (int o = 32; o > 0; o >>= 1) v += __shfl_down(v, o);
  if ((tid & 63) == 0) red[tid >> 6] = v;
  __syncthreads();
  if (tid == 0) stv(dout, OFF_FI_ + row, red[0] + red[1], isf);
}

// ---------------------------------------------------------------------------
// K2 v4: GRU bank (unchanged, passing)
// ---------------------------------------------------------------------------
__global__ __launch_bounds__(256)
void gru_scan4(const u16* __restrict__ xg, const void* __restrict__ W_ih,
               const void* __restrict__ W_hh, const void* __restrict__ b_ih,
               const void* __restrict__ b_hh, const u32* __restrict__ flag,
               u16* __restrict__ gruo) {
  const bool isf = (*flag != 0);
  const int tid = threadIdx.x;
  const int ric = tid >> 3;
  const int j   = tid & 7;
  const int rec = blockIdx.x * 32 + ric;
  const int b = rec >> 7, f = rec & 127;
  __shared__ __align__(16) float hbuf[32][8];
  float whr[8], whz[8], whn[8];
  #pragma unroll
  for (int k = 0; k < 8; ++k) {
    whr[k] = ldv(W_hh, (long)f * 192 + j * 8 + k, isf);
    whz[k] = ldv(W_hh, (long)f * 192 + (8 + j) * 8 + k, isf);
    whn[k] = ldv(W_hh, (long)f * 192 + (16 + j) * 8 + k, isf);
  }
  const float wir = ldv(W_ih, f * 24 + j, isf);
  const float wiz = ldv(W_ih, f * 24 + 8 + j, isf);
  const float win = ldv(W_ih, f * 24 + 16 + j, isf);
  const float cbr = ldv(b_ih, f * 24 + j, isf) + ldv(b_hh, f * 24 + j, isf);
  const float cbz = ldv(b_ih, f * 24 + 8 + j, isf) + ldv(b_hh, f * 24 + 8 + j, isf);
  const float bin_ = ldv(b_ih, f * 24 + 16 + j, isf);
  const float bhn_ = ldv(b_hh, f * 24 + 16 + j, isf);
  float h[8];
  #pragma unroll
  for (int k = 0; k < 8; ++k) h[k] = 0.f;
  const u16* xp = xg + (long)b * T_ * F_ + f;
  u16* op = gruo + (long)b * T_ * E_ + f * 8 + j;
  float xv = bf2f(xp[0]);
  for (int t = 0; t < T_; ++t) {
    float xn = (t + 1 < T_) ? bf2f(xp[(t + 1) * F_]) : 0.f;
    float ar = fmaf(xv, wir, cbr);
    float az = fmaf(xv, wiz, cbz);
    float an = bhn_;
    #pragma unroll
    for (int k = 0; k < 8; ++k) {
      ar = fmaf(h[k], whr[k], ar);
      az = fmaf(h[k], whz[k], az);
      an = fmaf(h[k], whn[k], an);
    }
    const float r = sigmoidf_(ar);
    const float z = sigmoidf_(az);
    const float a = fmaf(r, an, fmaf(xv, win, bin_));
    const float e = __expf(2.f * a);
    const float n = 1.f - 2.f / (e + 1.f);
    const float hn = fmaf(z, h[j] - n, n);
    op[(long)t * E_] = f2bf(hn);
    hbuf[ric][j] = hn;
    f32x4 h0 = *(const f32x4*)&hbuf[ric][0];
    f32x4 h1 = *(const f32x4*)&hbuf[ric][4];
    h[0] = h0[0]; h[1] = h0[1]; h[2] = h0[2]; h[3] = h0[3];
    h[4] = h1[0]; h[5] = h1[1]; h[6] = h1[2]; h[7] = h1[3];
    xv = xn;
  }
}

// ---------------------------------------------------------------------------
// bt-form MFMA GEMM (round-8 proven core): 128x128, BK=64, swizzled gld16.
// bm-fastest block order (lowest measured FETCH). EPI: 1=+bias. 
// ---------------------------------------------------------------------------
template <int EPI>
__global__ __launch_bounds__(256)
void gemm_bt(const u16* __restrict__ A, int lda,
             const u16* __restrict__ Bp, int ldb,
             u16* __restrict__ Cg, int ldc,
             const u16* __restrict__ bias,
             int K, int nbm) {
  const int bm = blockIdx.x % nbm, bn = blockIdx.x / nbm;
  const int w = threadIdx.x >> 6, lane = threadIdx.x & 63;
  __shared__ __align__(16) u16 As[128 * 64];
  __shared__ __align__(16) u16 Bs[128 * 64];
  const long m0 = (long)bm * 128, n0 = (long)bn * 128;
  const int wm = w >> 1, wn = w & 1;
  const int lr8 = lane >> 3;
  const int csw = ((lane & 7) ^ (lr8 & 7)) * 8;
  f32x4 acc[4][4] = {};
  const int nk = K >> 6;
  const int lr = lane & 15, lq = lane >> 4;
  for (int kt = 0; kt < nk; ++kt) {
    const int k0 = kt << 6;
    __syncthreads();
    #pragma unroll
    for (int c = 0; c < 4; ++c) {
      const int rb = w * 32 + c * 8;
      gld16((char*)As + rb * 128, A + (m0 + rb + lr8) * (long)lda + k0 + csw);
      gld16((char*)Bs + rb * 128, Bp + (n0 + rb + lr8) * (long)ldb + k0 + csw);
    }
    __syncthreads();
    #pragma unroll
    for (int sub = 0; sub < 2; ++sub) {
      const int ch = sub * 4 + lq;
      const int cof = ((ch ^ (lr & 7)) << 3);
      bf16x8 af[4], bfv[4];
      #pragma unroll
      for (int i = 0; i < 4; ++i)
        af[i] = *(const bf16x8*)&As[(wm * 64 + i * 16 + lr) * 64 + cof];
      #pragma unroll
      for (int i = 0; i < 4; ++i)
        bfv[i] = *(const bf16x8*)&Bs[(wn * 64 + i * 16 + lr) * 64 + cof];
      #pragma unroll
      for (int i = 0; i < 4; ++i) {
        #pragma unroll
        for (int j = 0; j < 4; ++j)
          acc[i][j] = __builtin_amdgcn_mfma_f32_16x16x32_bf16(af[i], bfv[j], acc[i][j], 0, 0, 0);
      }
    }
  }
  const int rq = lq * 4;
  #pragma unroll
  for (int j = 0; j < 4; ++j) {
    const long col = n0 + wn * 64 + j * 16 + lr;
    const float bv = (EPI >= 1) ? bf2f(bias[col]) : 0.f;
    #pragma unroll
    for (int i = 0; i < 4; ++i) {
      const long row0 = m0 + wm * 64 + i * 16 + rq;
      #pragma unroll
      for (int q = 0; q < 4; ++q)
        Cg[(row0 + q) * (long)ldc + col] = f2bf(acc[i][j][q] + bv);
    }
  }
}

// ---------------------------------------------------------------------------
// Fused tail: per block, 32 M-rows through h1 -> ffh -> y entirely in LDS.
//   h1  = mha @ wtO^T + bO            (K=1024, staged A, global-B frags)
//   ffh = gelu(h1 @ wtF1^T + bF1)     (K=256, A from LDS, global-B frags)
//   y   = h1 + ffh @ wtF2^T + bF2     (K=512, A from LDS, global-B frags)
// 4 waves (256 thr), grid = M/32 = 512 blocks. LDS 54KB -> 2 blocks/CU.
// Weights are L2-resident (<=0.5MB): direct bf16x8 global frag reads.
// ---------------------------------------------------------------------------
__global__ __launch_bounds__(256)
void fused_tail(const u16* __restrict__ MHA,
                const u16* __restrict__ wtO, const u16* __restrict__ wtF1,
                const u16* __restrict__ wtF2,
                const u16* __restrict__ bO, const u16* __restrict__ bF1,
                const u16* __restrict__ bF2,
                void* __restrict__ Y, const u32* __restrict__ flag) {
  const bool isf = (*flag != 0);
  const int w = threadIdx.x >> 6, lane = threadIdx.x & 63;
  const long m0 = (long)blockIdx.x * 32;
  __shared__ __align__(16) u16 Astg[32 * 64];    // 4KB
  __shared__ __align__(16) u16 h1s[32 * 264];    // 16.5KB
  __shared__ __align__(16) u16 ffhs[32 * 520];   // 32.5KB
  const int lr = lane & 15, lq = lane >> 4;
  const int rq = lq * 4;
  const int srow = w * 8 + (lane >> 3);
  const int csw = ((lane & 7) ^ ((lane >> 3) & 7)) * 8;
  // ---- sub1: h1[32][256], wave w -> cols w*64..+64 ----
  f32x4 acc1[2][4] = {};
  for (int kt = 0; kt < 16; ++kt) {
    const int k0 = kt << 6;
    __syncthreads();
    gld16(&Astg[w * 512], MHA + (m0 + srow) * 1024L + k0 + csw);
    __syncthreads();
    #pragma unroll
    for (int kk = 0; kk < 2; ++kk) {
      const int ch = kk * 4 + lq;
      const int cof = ((ch ^ (lr & 7)) << 3);
      bf16x8 af[2];
      #pragma unroll
      for (int i = 0; i < 2; ++i)
        af[i] = *(const bf16x8*)&Astg[(i * 16 + lr) * 64 + cof];
      #pragma unroll
      for (int j = 0; j < 4; ++j) {
        const int n = w * 64 + j * 16 + lr;
        bf16x8 bfv = *(const bf16x8*)(wtO + n * 1024L + k0 + kk * 32 + lq * 8);
        #pragma unroll
        for (int i = 0; i < 2; ++i)
          acc1[i][j] = __builtin_amdgcn_mfma_f32_16x16x32_bf16(af[i], bfv, acc1[i][j], 0, 0, 0);
      }
    }
  }
  __syncthreads();
  #pragma unroll
  for (int j = 0; j < 4; ++j) {
    const int col = w * 64 + j * 16 + lr;
    const float bv = bf2f(bO[col]);
    #pragma unroll
    for (int i = 0; i < 2; ++i)
      #pragma unroll
      for (int q = 0; q < 4; ++q)
        h1s[(i * 16 + rq + q) * 264 + col] = f2bf(acc1[i][j][q] + bv);
  }
  __syncthreads();
  // ---- sub2: ffh[32][512] = gelu(h1 @ wtF1^T + bF1), wave w -> cols w*128 ----
  f32x4 acc2[2][8] = {};
  for (int kt = 0; kt < 8; ++kt) {
    const int k0 = kt << 5;
    bf16x8 af[2];
    #pragma unroll
    for (int i = 0; i < 2; ++i)
      af[i] = *(const bf16x8*)&h1s[(i * 16 + lr) * 264 + k0 + lq * 8];
    #pragma unroll
    for (int j = 0; j < 8; ++j) {
      const int n = w * 128 + j * 16 + lr;
      bf16x8 bfv = *(const bf16x8*)(wtF1 + n * 256L + k0 + lq * 8);
      #pragma unroll
      for (int i = 0; i < 2; ++i)
        acc2[i][j] = __builtin_amdgcn_mfma_f32_16x16x32_bf16(af[i], bfv, acc2[i][j], 0, 0, 0);
    }
  }
  __syncthreads();
  #pragma unroll
  for (int j = 0; j < 8; ++j) {
    const int col = w * 128 + j * 16 + lr;
    const float bv = bf2f(bF1[col]);
    #pragma unroll
    for (int i = 0; i < 2; ++i)
      #pragma unroll
      for (int q = 0; q < 4; ++q)
        ffhs[(i * 16 + rq + q) * 520 + col] = f2bf(gelu_exact(acc2[i][j][q] + bv));
  }
  __syncthreads();
  // ---- sub3: y[32][256] = h1 + ffh @ wtF2^T + bF2, wave w -> cols w*64 ----
  f32x4 acc3[2][4] = {};
  for (int kt = 0; kt < 16; ++kt) {
    const int k0 = kt << 5;
    bf16x8 af[2];
    #pragma unroll
    for (int i = 0; i < 2; ++i)
      af[i] = *(const bf16x8*)&ffhs[(i * 16 + lr) * 520 + k0 + lq * 8];
    #pragma unroll
    for (int j = 0; j < 4; ++j) {
      const int n = w * 64 + j * 16 + lr;
      bf16x8 bfv = *(const bf16x8*)(wtF2 + n * 512L + k0 + lq * 8);
      #pragma unroll
      for (int i = 0; i < 2; ++i)
        acc3[i][j] = __builtin_amdgcn_mfma_f32_16x16x32_bf16(af[i], bfv, acc3[i][j], 0, 0, 0);
    }
  }
  #pragma unroll
  for (int j = 0; j < 4; ++j) {
    const int col = w * 64 + j * 16 + lr;
    const float bv = bf2f(bF2[col]);
    #pragma unroll
    for (int i = 0; i < 2; ++i)
      #pragma unroll
      for (int q = 0; q < 4; ++q) {
        const int rl = i * 16 + rq + q;
        const float v = acc3[i][j][q] + bv + bf2f(h1s[rl * 264 + col]);
        stv(Y, (m0 + rl) * 256L + col, v, isf);
      }
  }
}

// ---------------------------------------------------------------------------
// Fused attention (unchanged, passing)
// ---------------------------------------------------------------------------
__global__ __launch_bounds__(256)
void attn_fused(const u16* __restrict__ qkv, u16* __restrict__ ctx) {
  const int z = blockIdx.y, bb = z >> 2, hh = z & 3;
  const int w = threadIdx.x >> 6, lane = threadIdx.x & 63;
  const int tid = threadIdx.x;
  const long t0 = (long)blockIdx.x * 64;
  __shared__ __align__(16) u16 P1[10240];
  __shared__ __align__(16) u16 Pl[64 * 264];
  __shared__ __align__(16) u16 Vt[256 * 40];
  const u16* qb = qkv + (long)bb * T_ * 3 * E_ + hh * HD_;
  const u16* kb = qb + E_;
  const u16* vb = qb + 2 * E_;
  const int rr = lane >> 2, cc = lane & 3;
  const int lr = lane & 15, lq = lane >> 4, lk = lq * 8;
  f32x4 acc[16] = {};
  for (int kt = 0; kt < 8; ++kt) {
    const int k0 = kt * 32;
    __syncthreads();
    gld16((char*)P1 + w * 16 * 64, qb + (t0 + w * 16 + rr) * (3L * E_) + k0 + cc * 8);
    #pragma unroll
    for (int c = 0; c < 4; ++c) {
      const int rb = w * 64 + c * 16;
      gld16((char*)P1 + 4096 + rb * 64, kb + (long)(rb + rr) * (3L * E_) + k0 + cc * 8);
    }
    __syncthreads();
    bf16x8 aq = *(const bf16x8*)&P1[(w * 16 + lr) * 32 + lk];
    #pragma unroll
    for (int nt = 0; nt < 16; ++nt) {
      bf16x8 bk = *(const bf16x8*)&P1[2048 + (nt * 16 + lr) * 32 + lk];
      acc[nt] = __builtin_amdgcn_mfma_f32_16x16x32_bf16(aq, bk, acc[nt], 0, 0, 0);
    }
  }
  #pragma unroll
  for (int q = 0; q < 4; ++q) {
    float mx = -3.4e38f;
    #pragma unroll
    for (int nt = 0; nt < 16; ++nt) mx = fmaxf(mx, acc[nt][q]);
    mx = fmaxf(mx, __shfl_xor(mx, 1));
    mx = fmaxf(mx, __shfl_xor(mx, 2));
    mx = fmaxf(mx, __shfl_xor(mx, 4));
    mx = fmaxf(mx, __shfl_xor(mx, 8));
    float e[16], sum = 0.f;
    #pragma unroll
    for (int nt = 0; nt < 16; ++nt) {
      e[nt] = __expf((acc[nt][q] - mx) * 0.0625f);
      sum += e[nt];
    }
    sum += __shfl_xor(sum, 1);
    sum += __shfl_xor(sum, 2);
    sum += __shfl_xor(sum, 4);
    sum += __shfl_xor(sum, 8);
    const float inv = 1.f / sum;
    const int rowl = w * 16 + lq * 4 + q;
    #pragma unroll
    for (int nt = 0; nt < 16; ++nt)
      Pl[rowl * 264 + nt * 16 + lr] = f2bf(e[nt] * inv);
  }
  f32x4 acc2[16] = {};
  for (int st = 0; st < 8; ++st) {
    const int s0 = st * 32;
    __syncthreads();
    #pragma unroll
    for (int c = 0; c < 4; ++c) {
      const int rb = w * 8 + c * 2;
      gld16((char*)P1 + rb * 512, vb + (s0 + rb + (lane >> 5)) * (3L * E_) + (lane & 31) * 8);
    }
    __syncthreads();
    u16 col[32];
    #pragma unroll
    for (int si = 0; si < 32; ++si) col[si] = P1[si * 256 + tid];
    #pragma unroll
    for (int cq = 0; cq < 4; ++cq)
      *(uint4*)&Vt[tid * 40 + cq * 8] = *(const uint4*)&col[cq * 8];
    __syncthreads();
    bf16x8 pa = *(const bf16x8*)&Pl[(w * 16 + lr) * 264 + s0 + lk];
    #pragma unroll
    for (int nt = 0; nt < 16; ++nt) {
      bf16x8 bv = *(const bf16x8*)&Vt[(nt * 16 + lr) * 40 + lk];
      acc2[nt] = __builtin_amdgcn_mfma_f32_16x16x32_bf16(pa, bv, acc2[nt], 0, 0, 0);
    }
  }
  const int rq = lq * 4;
  #pragma unroll
  for (int nt = 0; nt < 16; ++nt) {
    const int cold = nt * 16 + lr;
    #pragma unroll
    for (int q = 0; q < 4; ++q) {
      const long row = t0 + w * 16 + rq + q;
      ctx[((long)bb * T_ + row) * E_ + hh * HD_ + cold] = f2bf(acc2[nt][q]);
    }
  }
}

// ---------------------------------------------------------------------------
extern "C" void kernel_launch(void* const* d_in, const int* in_sizes, int n_in,
                              void* d_out, int out_size, void* d_ws, size_t ws_size,
                              hipStream_t stream) {
  (void)in_sizes; (void)n_in; (void)out_size; (void)ws_size;
  char* ws = (char*)d_ws;
  // ws layout (bytes), peak 151MB (proven safe: round 2 wrote 165.7MB cleanly)
  u16* BIASA = (u16*)(ws + 0);
  u32* FLAG  = (u32*)(ws + 12288);
  u16* wtI   = (u16*)(ws + 65536);      // [3072][1024]
  u16* wtM   = (u16*)(ws + 6356992);    // [1024][1024]
  u16* wtO   = (u16*)(ws + 8454144);    // [256][1024]
  u16* wtF1  = (u16*)(ws + 8978432);    // [512][256]
  u16* wtF2  = (u16*)(ws + 9240576);    // [256][512]
  u16* XG    = (u16*)(ws + 9502720);    // [B,T,F]
  u16* GRUO  = (u16*)(ws + 16777216);   // [B,T,E] (dead after QKV gemm)
  u16* CTX   = GRUO;                    // [B,T,E] overlay
  u16* QKV   = (u16*)(ws + 50331648);   // [B,T,3E] (dead after attn)
  u16* MHA   = (u16*)(ws + 50331648);   // [B,T,E] overlay on dead QKV

  detect_dtype<<<1, 64, 0, stream>>>((const u16*)d_in[0], FLAG);

  convert_in<<<12, 256, 0, stream>>>(d_in[10], BIASA + 0,    3072, FLAG);
  convert_in<<<4,  256, 0, stream>>>(d_in[12], BIASA + 3072, 1024, FLAG);
  convert_in<<<1,  256, 0, stream>>>(d_in[14], BIASA + 4096, 256,  FLAG);
  convert_in<<<2,  256, 0, stream>>>(d_in[16], BIASA + 4352, 512,  FLAG);
  convert_in<<<1,  256, 0, stream>>>(d_in[18], BIASA + 4864, 256,  FLAG);

  dim3 tb(32, 8);
  transpose_cvt<<<dim3(3072 / 32, 1024 / 32), tb, 0, stream>>>(d_in[9],  wtI,  1024, 3072, FLAG);
  transpose_cvt<<<dim3(1024 / 32, 1024 / 32), tb, 0, stream>>>(d_in[11], wtM,  1024, 1024, FLAG);
  transpose_cvt<<<dim3(256 / 32, 1024 / 32),  tb, 0, stream>>>(d_in[13], wtO,  1024, 256,  FLAG);
  transpose_cvt<<<dim3(512 / 32, 256 / 32),   tb, 0, stream>>>(d_in[15], wtF1, 256,  512,  FLAG);
  transpose_cvt<<<dim3(256 / 32, 512 / 32),   tb, 0, stream>>>(d_in[17], wtF2, 512,  256,  FLAG);

  input_mlp2<<<B_ * T_, 128, 0, stream>>>(d_in[0], d_in[1], d_in[2], d_in[3], d_in[4],
                                          FLAG, XG, d_out);
  gru_scan4<<<256, 256, 0, stream>>>(XG, d_in[5], d_in[6], d_in[7], d_in[8], FLAG, GRUO);

  // qkv = gruo @ in_proj + b   (M=16384, N=3072, K=1024)
  gemm_bt<1><<<dim3(128 * 24, 1), 256, 0, stream>>>(GRUO, 1024, wtI, 1024,
      QKV, 3072, BIASA, 1024, 128);
  // fused attention -> CTX [B,T,E]
  attn_fused<<<dim3(4, B_ * NH_), 256, 0, stream>>>(QKV, CTX);
  // mha = ctx @ mha_out_w + b  (M=16384, N=1024, K=1024)
  gemm_bt<1><<<dim3(128 * 8, 1), 256, 0, stream>>>(CTX, 1024, wtM, 1024,
      MHA, 1024, BIASA + 3072, 1024, 128);
  // fused tail: h1 -> ffh -> y (final output, dtype-flagged)
  fused_tail<<<512, 256, 0, stream>>>(MHA, wtO, wtF1, wtF2,
      BIASA + 4096, BIASA + 4352, BIASA + 4864, d_out, FLAG);
}